// Round 7
// baseline (1015.214 us; speedup 1.0000x reference)
//
#include <hip/hip_runtime.h>

#define L_ 2
#define B_ 2
#define T_ 2048
#define C_ 1024
#define H_ 16
#define D_ 64
#define F_ 4096
#define NTOK 4096      // B*T
#define NELEM 4194304  // B*T*C

typedef unsigned short u16;
typedef __attribute__((ext_vector_type(8))) short short8;
typedef __attribute__((ext_vector_type(4))) float float4v;

__device__ __forceinline__ float bf2f(u16 u) {
  unsigned v = ((unsigned)u) << 16;
  return __builtin_bit_cast(float, v);
}
__device__ __forceinline__ u16 f2bf(float f) {
  unsigned u = __builtin_bit_cast(unsigned, f);
  u += 0x7FFFu + ((u >> 16) & 1u);   // round-to-nearest-even
  return (u16)(u >> 16);
}

// ---------------- elementwise ----------------
__global__ void k_copyf(const float* __restrict__ in, float* __restrict__ out) {
  const int i = blockIdx.x * 256 + threadIdx.x;
  out[i] = in[i];
}
__global__ void k_add(float* __restrict__ x, const u16* __restrict__ f) {
  const int i = blockIdx.x * 256 + threadIdx.x;
  x[i] += bf2f(f[i]);
}
__global__ void k_mix(float* __restrict__ x, const u16* __restrict__ attn,
                      const float* __restrict__ gates, const float* __restrict__ ret) {
  const int i = blockIdx.x * 256 + threadIdx.x;
  const int row = i >> 10;       // C=1024
  const int col = i & 1023;
  const int b = row >> 11;       // T=2048
  x[i] += gates[row * 2 + 0] * bf2f(attn[i]) + gates[row * 2 + 1] * ret[b * C_ + col];
}

// ---------------- RMSNorm: one block per row (f32 x, f32 gamma -> bf16 out) --------
__global__ __launch_bounds__(256) void k_rms(const float* __restrict__ x,
                                             const float* __restrict__ g,
                                             u16* __restrict__ out) {
  const int row = blockIdx.x;
  const float* xr = x + (size_t)row * C_;
  float s = 0.f;
  for (int c = threadIdx.x; c < C_; c += 256) { float v = xr[c]; s += v * v; }
#pragma unroll
  for (int o = 32; o; o >>= 1) s += __shfl_down(s, o);
  __shared__ float red[4];
  __shared__ float rsv;
  if ((threadIdx.x & 63) == 0) red[threadIdx.x >> 6] = s;
  __syncthreads();
  if (threadIdx.x == 0) {
    float t = red[0] + red[1] + red[2] + red[3];
    rsv = rsqrtf(t * (1.f / C_) + 1e-6f);
  }
  __syncthreads();
  const float rr = rsv;
  u16* orow = out + (size_t)row * C_;
  for (int c = threadIdx.x; c < C_; c += 256) orow[c] = f2bf(xr[c] * rr * g[c]);
}

// ---------------- transpose+convert: f32 (K,N) -> bf16 (N,K) ----------------
__global__ void k_transpose(const float* __restrict__ in, u16* __restrict__ out,
                            int K, int N) {
  __shared__ float tile[32][33];
  const int x = blockIdx.x * 32 + threadIdx.x;
  const int y0 = blockIdx.y * 32 + threadIdx.y;
#pragma unroll
  for (int i = 0; i < 32; i += 8) tile[threadIdx.y + i][threadIdx.x] = in[(size_t)(y0 + i) * N + x];
  __syncthreads();
  const int x2 = blockIdx.y * 32 + threadIdx.x;
  const int y2 = blockIdx.x * 32 + threadIdx.y;
#pragma unroll
  for (int i = 0; i < 32; i += 8) out[(size_t)(y2 + i) * K + x2] = f2bf(tile[threadIdx.x][threadIdx.y + i]);
}

// ---------------- V transpose: qkv v-part [b][j][h*64+d] -> Vt[(b*H+h)*64+d][j] ----
__global__ void k_vt(const u16* __restrict__ qkv, u16* __restrict__ Vt) {
  __shared__ u16 tile[32][34];
  const int jt = blockIdx.x;        // 0..63
  const int dt = blockIdx.y;        // 0..1
  const int bh = blockIdx.z;        // 0..31
  const int b = bh >> 4;
  const int h = bh & 15;
  const int tx = threadIdx.x, ty = threadIdx.y;
#pragma unroll
  for (int i = 0; i < 32; i += 8) {
    const int j = jt * 32 + ty + i;
    const int d = dt * 32 + tx;
    tile[ty + i][tx] = qkv[(size_t)(b * T_ + j) * (3 * C_) + 2 * C_ + h * D_ + d];
  }
  __syncthreads();
#pragma unroll
  for (int i = 0; i < 32; i += 8) {
    const int d = dt * 32 + ty + i;
    const int j = jt * 32 + tx;
    Vt[(size_t)(bh * D_ + d) * T_ + j] = tile[tx][ty + i];
  }
}

// ---------------- GEMM: C[M,N] = A[M,K] @ Bt[N,K]^T (bf16 in, bf16 out, f32 acc)
// 128x128 tile, BK=64, XOR-swizzled LDS (conflict-free, verified r6: 4.19M -> 0).
template <int MUL>
__global__ __launch_bounds__(256) void k_gemm_bt(const u16* __restrict__ A,
                                                 const u16* __restrict__ Bt,
                                                 u16* __restrict__ Cc,
                                                 const u16* __restrict__ mul,
                                                 int N, int K) {
  __shared__ __align__(16) u16 As[128 * 64];
  __shared__ __align__(16) u16 Bs[128 * 64];
  const int tid = threadIdx.x;
  const int wave = tid >> 6;
  const int lane = tid & 63;
  const int quad = lane >> 4;
  const int m16 = lane & 15;
  const int m0 = blockIdx.x * 128;
  const int n0 = blockIdx.y * 128;
  const int wm = (wave & 1) * 64;
  const int wn = (wave >> 1) * 64;
  const int srow = lane >> 3;             // 0..7
  const int sc = lane & 7;                // physical chunk
  const int scol = ((sc ^ srow) & 7) * 8; // logical k-offset (swizzle)
  const int csw = m16 & 7;                // read-side swizzle key

  float4v acc[4][4];
#pragma unroll
  for (int i = 0; i < 4; i++)
#pragma unroll
    for (int j = 0; j < 4; j++) acc[i][j] = (float4v){0.f, 0.f, 0.f, 0.f};

  for (int k0 = 0; k0 < K; k0 += 64) {
#pragma unroll
    for (int p = 0; p < 4; p++) {
      const int r = p * 32 + wave * 8;
      const u16* ga = A + (size_t)(m0 + r + srow) * K + k0 + scol;
      const u16* gb = Bt + (size_t)(n0 + r + srow) * K + k0 + scol;
      __builtin_amdgcn_global_load_lds((const __attribute__((address_space(1))) void*)ga,
                                       (__attribute__((address_space(3))) void*)((char*)As + r * 128),
                                       16, 0, 0);
      __builtin_amdgcn_global_load_lds((const __attribute__((address_space(1))) void*)gb,
                                       (__attribute__((address_space(3))) void*)((char*)Bs + r * 128),
                                       16, 0, 0);
    }
    __syncthreads();
#pragma unroll
    for (int s = 0; s < 2; s++) {
      const int chunk = ((s * 4 + quad) ^ csw) * 16;
      short8 af[4], bfr[4];
#pragma unroll
      for (int i = 0; i < 4; i++) {
        af[i] = *(const short8*)((const char*)As + (wm + i * 16 + m16) * 128 + chunk);
        bfr[i] = *(const short8*)((const char*)Bs + (wn + i * 16 + m16) * 128 + chunk);
      }
#pragma unroll
      for (int i = 0; i < 4; i++)
#pragma unroll
        for (int j = 0; j < 4; j++)
          acc[i][j] = __builtin_amdgcn_mfma_f32_16x16x32_bf16(af[i], bfr[j], acc[i][j], 0, 0, 0);
    }
    __syncthreads();
  }
#pragma unroll
  for (int i = 0; i < 4; i++) {
    const int row0 = m0 + wm + i * 16 + quad * 4;
#pragma unroll
    for (int j = 0; j < 4; j++) {
      const int col = n0 + wn + j * 16 + m16;
#pragma unroll
      for (int r = 0; r < 4; r++) {
        const size_t idx = (size_t)(row0 + r) * N + col;
        float v = acc[i][j][r];
        if (MUL == 1) v *= bf2f(mul[idx]);
        Cc[idx] = f2bf(v);
      }
    }
  }
}

// ---------------- fused SwiGLU dual-GEMM: act = silu(A@Btg^T) * (A@Btu^T) ----------
// A-tile staged ONCE per k-iter, two B-tiles, two acc sets; epilogue in-register.
__global__ __launch_bounds__(256) void k_gemm_swiglu(const u16* __restrict__ A,
                                                     const u16* __restrict__ Btg,
                                                     const u16* __restrict__ Btu,
                                                     u16* __restrict__ Cc,
                                                     int N, int K) {
  __shared__ __align__(16) u16 As[128 * 64];
  __shared__ __align__(16) u16 Bsg[128 * 64];
  __shared__ __align__(16) u16 Bsu[128 * 64];
  const int tid = threadIdx.x;
  const int wave = tid >> 6;
  const int lane = tid & 63;
  const int quad = lane >> 4;
  const int m16 = lane & 15;
  const int m0 = blockIdx.x * 128;
  const int n0 = blockIdx.y * 128;
  const int wm = (wave & 1) * 64;
  const int wn = (wave >> 1) * 64;
  const int srow = lane >> 3;
  const int sc = lane & 7;
  const int scol = ((sc ^ srow) & 7) * 8;
  const int csw = m16 & 7;

  float4v accg[4][4], accu[4][4];
#pragma unroll
  for (int i = 0; i < 4; i++)
#pragma unroll
    for (int j = 0; j < 4; j++) {
      accg[i][j] = (float4v){0.f, 0.f, 0.f, 0.f};
      accu[i][j] = (float4v){0.f, 0.f, 0.f, 0.f};
    }

  for (int k0 = 0; k0 < K; k0 += 64) {
#pragma unroll
    for (int p = 0; p < 4; p++) {
      const int r = p * 32 + wave * 8;
      const u16* ga = A + (size_t)(m0 + r + srow) * K + k0 + scol;
      const u16* gg = Btg + (size_t)(n0 + r + srow) * K + k0 + scol;
      const u16* gu = Btu + (size_t)(n0 + r + srow) * K + k0 + scol;
      __builtin_amdgcn_global_load_lds((const __attribute__((address_space(1))) void*)ga,
                                       (__attribute__((address_space(3))) void*)((char*)As + r * 128),
                                       16, 0, 0);
      __builtin_amdgcn_global_load_lds((const __attribute__((address_space(1))) void*)gg,
                                       (__attribute__((address_space(3))) void*)((char*)Bsg + r * 128),
                                       16, 0, 0);
      __builtin_amdgcn_global_load_lds((const __attribute__((address_space(1))) void*)gu,
                                       (__attribute__((address_space(3))) void*)((char*)Bsu + r * 128),
                                       16, 0, 0);
    }
    __syncthreads();
#pragma unroll
    for (int s = 0; s < 2; s++) {
      const int chunk = ((s * 4 + quad) ^ csw) * 16;
      short8 af[4], bg[4], bu[4];
#pragma unroll
      for (int i = 0; i < 4; i++) {
        af[i] = *(const short8*)((const char*)As + (wm + i * 16 + m16) * 128 + chunk);
        bg[i] = *(const short8*)((const char*)Bsg + (wn + i * 16 + m16) * 128 + chunk);
        bu[i] = *(const short8*)((const char*)Bsu + (wn + i * 16 + m16) * 128 + chunk);
      }
#pragma unroll
      for (int i = 0; i < 4; i++)
#pragma unroll
        for (int j = 0; j < 4; j++) {
          accg[i][j] = __builtin_amdgcn_mfma_f32_16x16x32_bf16(af[i], bg[j], accg[i][j], 0, 0, 0);
          accu[i][j] = __builtin_amdgcn_mfma_f32_16x16x32_bf16(af[i], bu[j], accu[i][j], 0, 0, 0);
        }
    }
    __syncthreads();
  }
#pragma unroll
  for (int i = 0; i < 4; i++) {
    const int row0 = m0 + wm + i * 16 + quad * 4;
#pragma unroll
    for (int j = 0; j < 4; j++) {
      const int col = n0 + wn + j * 16 + m16;
#pragma unroll
      for (int r = 0; r < 4; r++) {
        const float g = accg[i][j][r];
        const float u = accu[i][j][r];
        Cc[(size_t)(row0 + r) * N + col] = f2bf(u * g / (1.f + __expf(-g)));
      }
    }
  }
}

// ---------------- fused attention: one wave per (b, h, 16-query tile) -------------
__global__ __launch_bounds__(256) void k_attn(const u16* __restrict__ qkv,
                                              const u16* __restrict__ Vt,
                                              u16* __restrict__ o) {
  __shared__ u16 lds[4][16][290];
  const int wave = threadIdx.x >> 6;
  const int widG = blockIdx.x * 4 + wave;   // [0, 4096)
  const int lane = threadIdx.x & 63;
  const int quad = lane >> 4;
  const int c16 = lane & 15;
  const int qt = (widG & 127) * 16;
  const int h = (widG >> 7) & 15;
  const int b = widG >> 11;
  const size_t rs = 3 * C_;
  const int jt0 = qt - 256;

  const u16* qrow = qkv + (size_t)(b * T_ + qt + c16) * rs + h * D_ + quad * 8;
  const short8 a0 = *(const short8*)(qrow);
  const short8 a1 = *(const short8*)(qrow + 32);
  float4v S[17];
  const short8 z8 = (short8){0, 0, 0, 0, 0, 0, 0, 0};
#pragma unroll
  for (int t = 0; t < 17; t++) {
    if (jt0 + t * 16 + 15 < 0) { S[t] = (float4v){0.f, 0.f, 0.f, 0.f}; continue; }
    const int j = jt0 + t * 16 + c16;
    short8 b0 = z8, b1 = z8;
    if (j >= 0) {
      const u16* krow = qkv + (size_t)(b * T_ + j) * rs + C_ + h * D_ + quad * 8;
      b0 = *(const short8*)(krow);
      b1 = *(const short8*)(krow + 32);
    }
    float4v z = (float4v){0.f, 0.f, 0.f, 0.f};
    z = __builtin_amdgcn_mfma_f32_16x16x32_bf16(a0, b0, z, 0, 0, 0);
    z = __builtin_amdgcn_mfma_f32_16x16x32_bf16(a1, b1, z, 0, 0, 0);
    S[t] = z;
  }
#pragma unroll
  for (int r = 0; r < 4; r++) {
    const int q = qt + quad * 4 + r;
    float mx = -1.0e30f;
#pragma unroll
    for (int t = 0; t < 17; t++) {
      const int j = jt0 + t * 16 + c16;
      const int w = j - q + 255;
      const bool vis = (j >= 0) && (w >= 0) && (w < 256);
      if (vis) {
        const float s = S[t][r] * 0.125f;
        S[t][r] = s;
        mx = fmaxf(mx, s);
      } else {
        S[t][r] = -1.0e30f;
      }
    }
#pragma unroll
    for (int o2 = 1; o2 < 16; o2 <<= 1) mx = fmaxf(mx, __shfl_xor(mx, o2));
    float sum = 0.f;
#pragma unroll
    for (int t = 0; t < 17; t++) {
      const float e = (S[t][r] > -0.9e30f) ? __expf(S[t][r] - mx) : 0.f;
      S[t][r] = e;
      sum += e;
    }
#pragma unroll
    for (int o2 = 1; o2 < 16; o2 <<= 1) sum += __shfl_xor(sum, o2);
    const float inv = 1.f / fmaxf(sum, 1e-30f);
    const int prow = quad * 4 + r;
#pragma unroll
    for (int t = 0; t < 17; t++) lds[wave][prow][t * 16 + c16] = f2bf(S[t][r] * inv);
    lds[wave][prow][272 + c16] = 0;
  }
  __syncthreads();

  float4v acc[4];
#pragma unroll
  for (int md = 0; md < 4; md++) acc[md] = (float4v){0.f, 0.f, 0.f, 0.f};
  const u16* vtb = Vt + (size_t)((b * H_ + h) * D_) * T_;
  const uint* prow32 = (const uint*)(&lds[wave][c16][0]);
  union { short8 s8; uint u[4]; } bf;
#pragma unroll
  for (int c = 0; c < 9; c++) {
    const int jbase = jt0 + c * 32;
    if (jbase + 31 < 0) continue;
#pragma unroll
    for (int w2 = 0; w2 < 4; w2++) bf.u[w2] = prow32[c * 16 + quad * 4 + w2];
    int j0 = jbase + quad * 8;
    j0 = (j0 < 0) ? 0 : ((j0 > T_ - 8) ? (T_ - 8) : j0);
#pragma unroll
    for (int md = 0; md < 4; md++) {
      const short8 af = *(const short8*)(vtb + (size_t)(md * 16 + c16) * T_ + j0);
      acc[md] = __builtin_amdgcn_mfma_f32_16x16x32_bf16(af, bf.s8, acc[md], 0, 0, 0);
    }
  }
#pragma unroll
  for (int md = 0; md < 4; md++) {
    uint u0 = (uint)f2bf(acc[md][0]) | ((uint)f2bf(acc[md][1]) << 16);
    uint u1 = (uint)f2bf(acc[md][2]) | ((uint)f2bf(acc[md][3]) << 16);
    uint2 pk = make_uint2(u0, u1);
    u16* dst = o + (size_t)(b * T_ + qt + c16) * C_ + h * D_ + md * 16 + quad * 4;
    *(uint2*)dst = pk;
  }
}

// ---------------- gate logits + 2-way softmax (channel 1 pinned to -1e9) ----------
__global__ __launch_bounds__(256) void k_gate(const u16* __restrict__ h,
                                              const float* __restrict__ gW,
                                              const float* __restrict__ gb,
                                              float* __restrict__ gates) {
  const int row = blockIdx.x * 4 + (threadIdx.x >> 6);
  const int lane = threadIdx.x & 63;
  const u16* hr = h + (size_t)row * C_;
  float s0 = 0.f, s2 = 0.f;
  for (int k = lane; k < C_; k += 64) {
    const float hv = bf2f(hr[k]);
    s0 += hv * gW[k * 3 + 0];
    s2 += hv * gW[k * 3 + 2];
  }
#pragma unroll
  for (int o = 32; o; o >>= 1) { s0 += __shfl_down(s0, o); s2 += __shfl_down(s2, o); }
  if (lane == 0) {
    const float l0 = s0 + gb[0];
    const float l2 = s2 + gb[2];
    const float m = fmaxf(l0, l2);
    const float e0 = __expf(l0 - m), e2 = __expf(l2 - m);
    const float inv = 1.f / (e0 + e2);
    gates[row * 2 + 0] = e0 * inv;
    gates[row * 2 + 1] = e2 * inv;
  }
}

// ---------------- retrieval projection: ret[b][c] = sum_k rc[b][k]*rW[k][c] -------
__global__ void k_ret(const float* __restrict__ rc, const float* __restrict__ rW,
                      float* __restrict__ ret) {
  const int b = blockIdx.x >> 2;
  const int col = (blockIdx.x & 3) * 256 + threadIdx.x;
  float s = 0.f;
  for (int k = 0; k < C_; k++) s += rc[b * C_ + k] * rW[(size_t)k * C_ + col];
  ret[b * C_ + col] = s;
}

// ---------------- launcher ----------------
extern "C" void kernel_launch(void* const* d_in, const int* in_sizes, int n_in,
                              void* d_out, int out_size, void* d_ws, size_t ws_size,
                              hipStream_t stream) {
  (void)in_sizes; (void)n_in; (void)out_size; (void)ws_size;
  const float* xin  = (const float*)d_in[0];
  const float* rc   = (const float*)d_in[1];
  const float* n1g  = (const float*)d_in[2];
  const float* Wqkv = (const float*)d_in[3];
  const float* Wpro = (const float*)d_in[4];
  const float* gW   = (const float*)d_in[5];
  const float* gb   = (const float*)d_in[6];
  const float* rW   = (const float*)d_in[7];
  const float* n2g  = (const float*)d_in[8];
  const float* fgW  = (const float*)d_in[9];
  const float* fuW  = (const float*)d_in[10];
  const float* fdW  = (const float*)d_in[11];

  // ---- workspace layout: 56.06 MiB ----
  char* w = (char*)d_ws;
  float* gates = (float*)(w);                            // 32 KB
  float* retb  = (float*)(w + 32768);                    // 8 KB (pad to 64K)
  float* xf32  = (float*)(w + 65536);                    // 16.78 MB residual (f32)
  u16* hbuf    = (u16*)(w + 65536 + (size_t)NELEM * 4);  // 8.39 MB h | attn_out | ffn_out
  u16* big     = hbuf + NELEM;                           // 33.55 MB region
  u16* qkv  = big;                          // 25.17 MB (attn phase)
  u16* obuf = big + (size_t)NTOK * 3 * C_;  // 8.39 MB  (attn phase)
  u16* gbuf = big;                          // 33.55 MB (FFN phase)
  // d_out (16.78 MB f32) doubles as scratch: wT lower half, Vt/wT2 upper half.
  // (Vt is rebuilt by k_vt before every k_attn; wT2 only lives during FFN.)
  u16* wT  = (u16*)d_out;                    // 8.39 MB
  u16* Vt  = (u16*)d_out + (size_t)NELEM;    // 8.39 MB: [B*H*D][T] bf16
  u16* wT2 = Vt;                             // FFN-phase alias

  k_copyf<<<NELEM / 256, 256, 0, stream>>>(xin, xf32);

  for (int l = 0; l < L_; l++) {
    k_rms<<<NTOK, 256, 0, stream>>>(xf32, n1g + l * C_, hbuf);
    // qkv = h @ Wqkv
    k_transpose<<<dim3(3 * C_ / 32, C_ / 32), dim3(32, 8), 0, stream>>>(
        Wqkv + (size_t)l * C_ * 3 * C_, wT, C_, 3 * C_);
    k_gemm_bt<0><<<dim3(NTOK / 128, 3 * C_ / 128), 256, 0, stream>>>(
        hbuf, wT, qkv, nullptr, 3 * C_, C_);
    // gates (last reader of h before hbuf reuse)
    k_gate<<<NTOK / 4, 256, 0, stream>>>(hbuf, gW + (size_t)l * C_ * 3, gb + l * 3, gates);
    // fused attention
    k_vt<<<dim3(64, 2, 32), dim3(32, 8), 0, stream>>>(qkv, Vt);
    k_attn<<<1024, 256, 0, stream>>>(qkv, Vt, obuf);
    // attn_out = o @ Wproj  -> hbuf (h dead)
    k_transpose<<<dim3(C_ / 32, C_ / 32), dim3(32, 8), 0, stream>>>(
        Wpro + (size_t)l * C_ * C_, wT, C_, C_);
    k_gemm_bt<0><<<dim3(NTOK / 128, C_ / 128), 256, 0, stream>>>(
        obuf, wT, hbuf, nullptr, C_, C_);
    // retrieval + mix
    k_ret<<<8, 256, 0, stream>>>(rc, rW + (size_t)l * C_ * C_, retb);
    k_mix<<<NELEM / 256, 256, 0, stream>>>(xf32, hbuf, gates, retb);
    // FFN: gbuf = silu(h2@Wg)*(h2@Wu) in ONE fused dual-B GEMM; hbuf = gbuf@Wd
    k_rms<<<NTOK, 256, 0, stream>>>(xf32, n2g + l * C_, hbuf);
    k_transpose<<<dim3(F_ / 32, C_ / 32), dim3(32, 8), 0, stream>>>(
        fgW + (size_t)l * C_ * F_, wT, C_, F_);
    k_transpose<<<dim3(F_ / 32, C_ / 32), dim3(32, 8), 0, stream>>>(
        fuW + (size_t)l * C_ * F_, wT2, C_, F_);
    k_gemm_swiglu<<<dim3(NTOK / 128, F_ / 128), 256, 0, stream>>>(
        hbuf, wT, wT2, gbuf, F_, C_);
    k_transpose<<<dim3(C_ / 32, F_ / 32), dim3(32, 8), 0, stream>>>(
        fdW + (size_t)l * F_ * C_, wT, F_, C_);
    k_gemm_bt<0><<<dim3(NTOK / 128, C_ / 128), 256, 0, stream>>>(
        gbuf, wT, hbuf, nullptr, C_, F_);
    k_add<<<NELEM / 256, 256, 0, stream>>>(xf32, hbuf);
  }

  k_copyf<<<NELEM / 256, 256, 0, stream>>>(xf32, (float*)d_out);
}

// Round 8
// 899.813 us; speedup vs baseline: 1.1282x; 1.1282x over previous
//
#include <hip/hip_runtime.h>

#define L_ 2
#define B_ 2
#define T_ 2048
#define C_ 1024
#define H_ 16
#define D_ 64
#define F_ 4096
#define NTOK 4096      // B*T
#define NELEM 4194304  // B*T*C

typedef unsigned short u16;
typedef __attribute__((ext_vector_type(8))) short short8;
typedef __attribute__((ext_vector_type(4))) float float4v;

__device__ __forceinline__ float bf2f(u16 u) {
  unsigned v = ((unsigned)u) << 16;
  return __builtin_bit_cast(float, v);
}
__device__ __forceinline__ u16 f2bf(float f) {
  unsigned u = __builtin_bit_cast(unsigned, f);
  u += 0x7FFFu + ((u >> 16) & 1u);   // round-to-nearest-even
  return (u16)(u >> 16);
}

// ---------------- elementwise ----------------
__global__ void k_copyf(const float* __restrict__ in, float* __restrict__ out) {
  const int i = blockIdx.x * 256 + threadIdx.x;
  out[i] = in[i];
}

// ---------------- RMSNorm variants (block per row) ----------------
// Common body: given row values v[0..3] (per-thread, stride 256), reduce, write bf16.
__device__ __forceinline__ void rms_tail(float* vloc, const float* __restrict__ g,
                                         u16* __restrict__ orow) {
  float s = vloc[0] * vloc[0] + vloc[1] * vloc[1] + vloc[2] * vloc[2] + vloc[3] * vloc[3];
#pragma unroll
  for (int o = 32; o; o >>= 1) s += __shfl_down(s, o);
  __shared__ float red[4];
  __shared__ float rsv;
  if ((threadIdx.x & 63) == 0) red[threadIdx.x >> 6] = s;
  __syncthreads();
  if (threadIdx.x == 0) {
    float t = red[0] + red[1] + red[2] + red[3];
    rsv = rsqrtf(t * (1.f / C_) + 1e-6f);
  }
  __syncthreads();
  const float rr = rsv;
#pragma unroll
  for (int i = 0; i < 4; i++) {
    const int c = threadIdx.x + i * 256;
    orow[c] = f2bf(vloc[i] * rr * g[c]);
  }
}

// layer-0 first norm: reads xin, ALSO initializes xf32
__global__ __launch_bounds__(256) void k_rms_first(const float* __restrict__ xin,
                                                   const float* __restrict__ g,
                                                   float* __restrict__ x,
                                                   u16* __restrict__ out) {
  const int row = blockIdx.x;
  const float* sr = xin + (size_t)row * C_;
  float* xr = x + (size_t)row * C_;
  float vloc[4];
#pragma unroll
  for (int i = 0; i < 4; i++) {
    const int c = threadIdx.x + i * 256;
    const float v = sr[c];
    vloc[i] = v;
    xr[c] = v;
  }
  rms_tail(vloc, g, out + (size_t)row * C_);
}

// plain norm (layer-1 first norm)
__global__ __launch_bounds__(256) void k_rms(const float* __restrict__ x,
                                             const float* __restrict__ g,
                                             u16* __restrict__ out) {
  const int row = blockIdx.x;
  const float* xr = x + (size_t)row * C_;
  float vloc[4];
#pragma unroll
  for (int i = 0; i < 4; i++) vloc[i] = xr[threadIdx.x + i * 256];
  rms_tail(vloc, g, out + (size_t)row * C_);
}

// second norm + fused retrieval-mix: x += g2*ret (write back), then rms -> out
__global__ __launch_bounds__(256) void k_rms2mix(float* __restrict__ x,
                                                 const float* __restrict__ gates,
                                                 const float* __restrict__ ret,
                                                 const float* __restrict__ g,
                                                 u16* __restrict__ out) {
  const int row = blockIdx.x;
  const int b = row >> 11;   // T=2048
  const float g2 = gates[row * 2 + 1];
  const float* rr_ = ret + b * C_;
  float* xr = x + (size_t)row * C_;
  float vloc[4];
#pragma unroll
  for (int i = 0; i < 4; i++) {
    const int c = threadIdx.x + i * 256;
    const float v = xr[c] + g2 * rr_[c];
    vloc[i] = v;
    xr[c] = v;
  }
  rms_tail(vloc, g, out + (size_t)row * C_);
}

// ---------------- batched transpose+convert: two f32 (K,N) -> bf16 (N,K) ----------
__global__ void k_tr2(const float* __restrict__ s0, u16* __restrict__ d0,
                      int K0, int N0, int t0,
                      const float* __restrict__ s1, u16* __restrict__ d1,
                      int K1, int N1) {
  __shared__ float tile[32][33];
  int t = blockIdx.x;
  const float* src; u16* dst; int K, N;
  if (t < t0) { src = s0; dst = d0; K = K0; N = N0; }
  else { t -= t0; src = s1; dst = d1; K = K1; N = N1; }
  const int ntx = N >> 5;
  const int tx = t % ntx, ty = t / ntx;
  const int x = tx * 32 + threadIdx.x;
  const int y0 = ty * 32 + threadIdx.y;
#pragma unroll
  for (int i = 0; i < 32; i += 8) tile[threadIdx.y + i][threadIdx.x] = src[(size_t)(y0 + i) * N + x];
  __syncthreads();
  const int x2 = ty * 32 + threadIdx.x;
  const int y2 = tx * 32 + threadIdx.y;
#pragma unroll
  for (int i = 0; i < 32; i += 8) dst[(size_t)(y2 + i) * K + x2] = f2bf(tile[threadIdx.x][threadIdx.y + i]);
}

// single transpose (fd)
__global__ void k_tr1(const float* __restrict__ in, u16* __restrict__ out, int K, int N) {
  __shared__ float tile[32][33];
  const int ntx = N >> 5;
  const int tx = blockIdx.x % ntx, ty = blockIdx.x / ntx;
  const int x = tx * 32 + threadIdx.x;
  const int y0 = ty * 32 + threadIdx.y;
#pragma unroll
  for (int i = 0; i < 32; i += 8) tile[threadIdx.y + i][threadIdx.x] = in[(size_t)(y0 + i) * N + x];
  __syncthreads();
  const int x2 = ty * 32 + threadIdx.x;
  const int y2 = tx * 32 + threadIdx.y;
#pragma unroll
  for (int i = 0; i < 32; i += 8) out[(size_t)(y2 + i) * K + x2] = f2bf(tile[threadIdx.x][threadIdx.y + i]);
}

// ---------------- V transpose: qkv v-part [b][j][h*64+d] -> Vt[(b*H+h)*64+d][j] ----
__global__ void k_vt(const u16* __restrict__ qkv, u16* __restrict__ Vt) {
  __shared__ u16 tile[32][34];
  const int jt = blockIdx.x;
  const int dt = blockIdx.y;
  const int bh = blockIdx.z;
  const int b = bh >> 4;
  const int h = bh & 15;
  const int tx = threadIdx.x, ty = threadIdx.y;
#pragma unroll
  for (int i = 0; i < 32; i += 8) {
    const int j = jt * 32 + ty + i;
    const int d = dt * 32 + tx;
    tile[ty + i][tx] = qkv[(size_t)(b * T_ + j) * (3 * C_) + 2 * C_ + h * D_ + d];
  }
  __syncthreads();
#pragma unroll
  for (int i = 0; i < 32; i += 8) {
    const int d = dt * 32 + ty + i;
    const int j = jt * 32 + tx;
    Vt[(size_t)(bh * D_ + d) * T_ + j] = tile[tx][ty + i];
  }
}

// ---------------- GEMM: 128x128 tile, BK=64, XOR-swizzled LDS (conflict-free) ------
// Split-K via gridDim.z (each z-slice covers K/gridDim.z).
// EPI=0: Cc[idx] = bf16(v)
// EPI=1: unsafeAtomicAdd(&Xf[idx], gates[row*2] * v)   (proj: gated residual add)
// EPI=2: unsafeAtomicAdd(&Xf[idx], v)                  (down: residual add)
template <int EPI>
__global__ __launch_bounds__(256) void k_gemm_bt(const u16* __restrict__ A,
                                                 const u16* __restrict__ Bt,
                                                 u16* __restrict__ Cc,
                                                 float* __restrict__ Xf,
                                                 const float* __restrict__ gates,
                                                 int N, int K) {
  __shared__ __align__(16) u16 As[128 * 64];
  __shared__ __align__(16) u16 Bs[128 * 64];
  const int tid = threadIdx.x;
  const int wave = tid >> 6;
  const int lane = tid & 63;
  const int quad = lane >> 4;
  const int m16 = lane & 15;
  const int m0 = blockIdx.x * 128;
  const int n0 = blockIdx.y * 128;
  const int wm = (wave & 1) * 64;
  const int wn = (wave >> 1) * 64;
  const int srow = lane >> 3;
  const int sc = lane & 7;
  const int scol = ((sc ^ srow) & 7) * 8;
  const int csw = m16 & 7;
  const int Kslice = K / gridDim.z;
  const int kbeg = blockIdx.z * Kslice;

  float4v acc[4][4];
#pragma unroll
  for (int i = 0; i < 4; i++)
#pragma unroll
    for (int j = 0; j < 4; j++) acc[i][j] = (float4v){0.f, 0.f, 0.f, 0.f};

  for (int k0 = kbeg; k0 < kbeg + Kslice; k0 += 64) {
#pragma unroll
    for (int p = 0; p < 4; p++) {
      const int r = p * 32 + wave * 8;
      const u16* ga = A + (size_t)(m0 + r + srow) * K + k0 + scol;
      const u16* gb = Bt + (size_t)(n0 + r + srow) * K + k0 + scol;
      __builtin_amdgcn_global_load_lds((const __attribute__((address_space(1))) void*)ga,
                                       (__attribute__((address_space(3))) void*)((char*)As + r * 128),
                                       16, 0, 0);
      __builtin_amdgcn_global_load_lds((const __attribute__((address_space(1))) void*)gb,
                                       (__attribute__((address_space(3))) void*)((char*)Bs + r * 128),
                                       16, 0, 0);
    }
    __syncthreads();
#pragma unroll
    for (int s = 0; s < 2; s++) {
      const int chunk = ((s * 4 + quad) ^ csw) * 16;
      short8 af[4], bfr[4];
#pragma unroll
      for (int i = 0; i < 4; i++) {
        af[i] = *(const short8*)((const char*)As + (wm + i * 16 + m16) * 128 + chunk);
        bfr[i] = *(const short8*)((const char*)Bs + (wn + i * 16 + m16) * 128 + chunk);
      }
#pragma unroll
      for (int i = 0; i < 4; i++)
#pragma unroll
        for (int j = 0; j < 4; j++)
          acc[i][j] = __builtin_amdgcn_mfma_f32_16x16x32_bf16(af[i], bfr[j], acc[i][j], 0, 0, 0);
    }
    __syncthreads();
  }
#pragma unroll
  for (int i = 0; i < 4; i++) {
    const int row0 = m0 + wm + i * 16 + quad * 4;
#pragma unroll
    for (int j = 0; j < 4; j++) {
      const int col = n0 + wn + j * 16 + m16;
#pragma unroll
      for (int r = 0; r < 4; r++) {
        const size_t idx = (size_t)(row0 + r) * N + col;
        const float v = acc[i][j][r];
        if (EPI == 0) Cc[idx] = f2bf(v);
        else if (EPI == 1) unsafeAtomicAdd(&Xf[idx], gates[(row0 + r) * 2] * v);
        else unsafeAtomicAdd(&Xf[idx], v);
      }
    }
  }
}

// ---------------- fused SwiGLU dual-GEMM: act = silu(A@Btg^T) * (A@Btu^T) ----------
__global__ __launch_bounds__(256) void k_gemm_swiglu(const u16* __restrict__ A,
                                                     const u16* __restrict__ Btg,
                                                     const u16* __restrict__ Btu,
                                                     u16* __restrict__ Cc,
                                                     int N, int K) {
  __shared__ __align__(16) u16 As[128 * 64];
  __shared__ __align__(16) u16 Bsg[128 * 64];
  __shared__ __align__(16) u16 Bsu[128 * 64];
  const int tid = threadIdx.x;
  const int wave = tid >> 6;
  const int lane = tid & 63;
  const int quad = lane >> 4;
  const int m16 = lane & 15;
  const int m0 = blockIdx.x * 128;
  const int n0 = blockIdx.y * 128;
  const int wm = (wave & 1) * 64;
  const int wn = (wave >> 1) * 64;
  const int srow = lane >> 3;
  const int sc = lane & 7;
  const int scol = ((sc ^ srow) & 7) * 8;
  const int csw = m16 & 7;

  float4v accg[4][4], accu[4][4];
#pragma unroll
  for (int i = 0; i < 4; i++)
#pragma unroll
    for (int j = 0; j < 4; j++) {
      accg[i][j] = (float4v){0.f, 0.f, 0.f, 0.f};
      accu[i][j] = (float4v){0.f, 0.f, 0.f, 0.f};
    }

  for (int k0 = 0; k0 < K; k0 += 64) {
#pragma unroll
    for (int p = 0; p < 4; p++) {
      const int r = p * 32 + wave * 8;
      const u16* ga = A + (size_t)(m0 + r + srow) * K + k0 + scol;
      const u16* gg = Btg + (size_t)(n0 + r + srow) * K + k0 + scol;
      const u16* gu = Btu + (size_t)(n0 + r + srow) * K + k0 + scol;
      __builtin_amdgcn_global_load_lds((const __attribute__((address_space(1))) void*)ga,
                                       (__attribute__((address_space(3))) void*)((char*)As + r * 128),
                                       16, 0, 0);
      __builtin_amdgcn_global_load_lds((const __attribute__((address_space(1))) void*)gg,
                                       (__attribute__((address_space(3))) void*)((char*)Bsg + r * 128),
                                       16, 0, 0);
      __builtin_amdgcn_global_load_lds((const __attribute__((address_space(1))) void*)gu,
                                       (__attribute__((address_space(3))) void*)((char*)Bsu + r * 128),
                                       16, 0, 0);
    }
    __syncthreads();
#pragma unroll
    for (int s = 0; s < 2; s++) {
      const int chunk = ((s * 4 + quad) ^ csw) * 16;
      short8 af[4], bg[4], bu[4];
#pragma unroll
      for (int i = 0; i < 4; i++) {
        af[i] = *(const short8*)((const char*)As + (wm + i * 16 + m16) * 128 + chunk);
        bg[i] = *(const short8*)((const char*)Bsg + (wn + i * 16 + m16) * 128 + chunk);
        bu[i] = *(const short8*)((const char*)Bsu + (wn + i * 16 + m16) * 128 + chunk);
      }
#pragma unroll
      for (int i = 0; i < 4; i++)
#pragma unroll
        for (int j = 0; j < 4; j++) {
          accg[i][j] = __builtin_amdgcn_mfma_f32_16x16x32_bf16(af[i], bg[j], accg[i][j], 0, 0, 0);
          accu[i][j] = __builtin_amdgcn_mfma_f32_16x16x32_bf16(af[i], bu[j], accu[i][j], 0, 0, 0);
        }
    }
    __syncthreads();
  }
#pragma unroll
  for (int i = 0; i < 4; i++) {
    const int row0 = m0 + wm + i * 16 + quad * 4;
#pragma unroll
    for (int j = 0; j < 4; j++) {
      const int col = n0 + wn + j * 16 + m16;
#pragma unroll
      for (int r = 0; r < 4; r++) {
        const float g = accg[i][j][r];
        const float u = accu[i][j][r];
        Cc[(size_t)(row0 + r) * N + col] = f2bf(u * g / (1.f + __expf(-g)));
      }
    }
  }
}

// ---------------- fused attention: one wave per (b, h, 16-query tile) -------------
__global__ __launch_bounds__(256) void k_attn(const u16* __restrict__ qkv,
                                              const u16* __restrict__ Vt,
                                              u16* __restrict__ o) {
  __shared__ u16 lds[4][16][290];
  const int wave = threadIdx.x >> 6;
  const int widG = blockIdx.x * 4 + wave;
  const int lane = threadIdx.x & 63;
  const int quad = lane >> 4;
  const int c16 = lane & 15;
  const int qt = (widG & 127) * 16;
  const int h = (widG >> 7) & 15;
  const int b = widG >> 11;
  const size_t rs = 3 * C_;
  const int jt0 = qt - 256;

  const u16* qrow = qkv + (size_t)(b * T_ + qt + c16) * rs + h * D_ + quad * 8;
  const short8 a0 = *(const short8*)(qrow);
  const short8 a1 = *(const short8*)(qrow + 32);
  float4v S[17];
  const short8 z8 = (short8){0, 0, 0, 0, 0, 0, 0, 0};
#pragma unroll
  for (int t = 0; t < 17; t++) {
    if (jt0 + t * 16 + 15 < 0) { S[t] = (float4v){0.f, 0.f, 0.f, 0.f}; continue; }
    const int j = jt0 + t * 16 + c16;
    short8 b0 = z8, b1 = z8;
    if (j >= 0) {
      const u16* krow = qkv + (size_t)(b * T_ + j) * rs + C_ + h * D_ + quad * 8;
      b0 = *(const short8*)(krow);
      b1 = *(const short8*)(krow + 32);
    }
    float4v z = (float4v){0.f, 0.f, 0.f, 0.f};
    z = __builtin_amdgcn_mfma_f32_16x16x32_bf16(a0, b0, z, 0, 0, 0);
    z = __builtin_amdgcn_mfma_f32_16x16x32_bf16(a1, b1, z, 0, 0, 0);
    S[t] = z;
  }
#pragma unroll
  for (int r = 0; r < 4; r++) {
    const int q = qt + quad * 4 + r;
    float mx = -1.0e30f;
#pragma unroll
    for (int t = 0; t < 17; t++) {
      const int j = jt0 + t * 16 + c16;
      const int w = j - q + 255;
      const bool vis = (j >= 0) && (w >= 0) && (w < 256);
      if (vis) {
        const float s = S[t][r] * 0.125f;
        S[t][r] = s;
        mx = fmaxf(mx, s);
      } else {
        S[t][r] = -1.0e30f;
      }
    }
#pragma unroll
    for (int o2 = 1; o2 < 16; o2 <<= 1) mx = fmaxf(mx, __shfl_xor(mx, o2));
    float sum = 0.f;
#pragma unroll
    for (int t = 0; t < 17; t++) {
      const float e = (S[t][r] > -0.9e30f) ? __expf(S[t][r] - mx) : 0.f;
      S[t][r] = e;
      sum += e;
    }
#pragma unroll
    for (int o2 = 1; o2 < 16; o2 <<= 1) sum += __shfl_xor(sum, o2);
    const float inv = 1.f / fmaxf(sum, 1e-30f);
    const int prow = quad * 4 + r;
#pragma unroll
    for (int t = 0; t < 17; t++) lds[wave][prow][t * 16 + c16] = f2bf(S[t][r] * inv);
    lds[wave][prow][272 + c16] = 0;
  }
  __syncthreads();

  float4v acc[4];
#pragma unroll
  for (int md = 0; md < 4; md++) acc[md] = (float4v){0.f, 0.f, 0.f, 0.f};
  const u16* vtb = Vt + (size_t)((b * H_ + h) * D_) * T_;
  const uint* prow32 = (const uint*)(&lds[wave][c16][0]);
  union { short8 s8; uint u[4]; } bf;
#pragma unroll
  for (int c = 0; c < 9; c++) {
    const int jbase = jt0 + c * 32;
    if (jbase + 31 < 0) continue;
#pragma unroll
    for (int w2 = 0; w2 < 4; w2++) bf.u[w2] = prow32[c * 16 + quad * 4 + w2];
    int j0 = jbase + quad * 8;
    j0 = (j0 < 0) ? 0 : ((j0 > T_ - 8) ? (T_ - 8) : j0);
#pragma unroll
    for (int md = 0; md < 4; md++) {
      const short8 af = *(const short8*)(vtb + (size_t)(md * 16 + c16) * T_ + j0);
      acc[md] = __builtin_amdgcn_mfma_f32_16x16x32_bf16(af, bf.s8, acc[md], 0, 0, 0);
    }
  }
#pragma unroll
  for (int md = 0; md < 4; md++) {
    uint u0 = (uint)f2bf(acc[md][0]) | ((uint)f2bf(acc[md][1]) << 16);
    uint u1 = (uint)f2bf(acc[md][2]) | ((uint)f2bf(acc[md][3]) << 16);
    uint2 pk = make_uint2(u0, u1);
    u16* dst = o + (size_t)(b * T_ + qt + c16) * C_ + h * D_ + md * 16 + quad * 4;
    *(uint2*)dst = pk;
  }
}

// ---------------- gate logits + 2-way softmax (channel 1 pinned to -1e9) ----------
__global__ __launch_bounds__(256) void k_gate(const u16* __restrict__ h,
                                              const float* __restrict__ gW,
                                              const float* __restrict__ gb,
                                              float* __restrict__ gates) {
  const int row = blockIdx.x * 4 + (threadIdx.x >> 6);
  const int lane = threadIdx.x & 63;
  const u16* hr = h + (size_t)row * C_;
  float s0 = 0.f, s2 = 0.f;
  for (int k = lane; k < C_; k += 64) {
    const float hv = bf2f(hr[k]);
    s0 += hv * gW[k * 3 + 0];
    s2 += hv * gW[k * 3 + 2];
  }
#pragma unroll
  for (int o = 32; o; o >>= 1) { s0 += __shfl_down(s0, o); s2 += __shfl_down(s2, o); }
  if (lane == 0) {
    const float l0 = s0 + gb[0];
    const float l2 = s2 + gb[2];
    const float m = fmaxf(l0, l2);
    const float e0 = __expf(l0 - m), e2 = __expf(l2 - m);
    const float inv = 1.f / (e0 + e2);
    gates[row * 2 + 0] = e0 * inv;
    gates[row * 2 + 1] = e2 * inv;
  }
}

// ---------------- both layers' retrieval projections in one launch ---------------
__global__ void k_ret2(const float* __restrict__ rc, const float* __restrict__ rW,
                       float* __restrict__ ret) {
  const int l = blockIdx.x >> 3;
  const int bid = blockIdx.x & 7;
  const int b = bid >> 2;
  const int col = (bid & 3) * 256 + threadIdx.x;
  const float* rWl = rW + (size_t)l * C_ * C_;
  float s = 0.f;
  for (int k = 0; k < C_; k++) s += rc[b * C_ + k] * rWl[(size_t)k * C_ + col];
  ret[(size_t)l * B_ * C_ + b * C_ + col] = s;
}

// ---------------- launcher ----------------
extern "C" void kernel_launch(void* const* d_in, const int* in_sizes, int n_in,
                              void* d_out, int out_size, void* d_ws, size_t ws_size,
                              hipStream_t stream) {
  (void)in_sizes; (void)n_in; (void)out_size; (void)ws_size;
  const float* xin  = (const float*)d_in[0];
  const float* rc   = (const float*)d_in[1];
  const float* n1g  = (const float*)d_in[2];
  const float* Wqkv = (const float*)d_in[3];
  const float* Wpro = (const float*)d_in[4];
  const float* gW   = (const float*)d_in[5];
  const float* gb   = (const float*)d_in[6];
  const float* rW   = (const float*)d_in[7];
  const float* n2g  = (const float*)d_in[8];
  const float* fgW  = (const float*)d_in[9];
  const float* fuW  = (const float*)d_in[10];
  const float* fdW  = (const float*)d_in[11];

  // ---- workspace layout: 56.06 MiB ----
  char* w = (char*)d_ws;
  float* gates = (float*)(w);                            // 32 KB (per-layer, reused)
  float* retb  = (float*)(w + 32768);                    // 16 KB: [L][B][C]
  float* xf32  = (float*)(w + 65536);                    // 16.78 MB residual (f32)
  u16* hbuf    = (u16*)(w + 65536 + (size_t)NELEM * 4);  // 8.39 MB h | h2 | fd^T
  u16* big     = hbuf + NELEM;                           // 33.55 MB region
  u16* qkv  = big;                          // 25.17 MB (attn phase)
  u16* obuf = big + (size_t)NTOK * 3 * C_;  // 8.39 MB  (attn phase)
  u16* gbuf = big;                          // 33.55 MB (FFN phase)
  // d_out (16.78 MB) scratch: lower = Wqkv^T+Wproj^T | fg^T; upper = Vt | fu^T
  u16* wT  = (u16*)d_out;                    // 8.39 MB
  u16* wTp = wT + (size_t)3 * C_ * C_;       // Wproj^T (2.1 MB tail of lower half)
  u16* Vt  = (u16*)d_out + (size_t)NELEM;    // 8.39 MB upper half
  u16* wT2 = Vt;                             // FFN alias

  k_ret2<<<16, 256, 0, stream>>>(rc, rW, retb);  // both layers, input-only

  for (int l = 0; l < L_; l++) {
    // h = rms(x)*g1  (layer 0 also initializes xf32 from xin)
    if (l == 0)
      k_rms_first<<<NTOK, 256, 0, stream>>>(xin, n1g, xf32, hbuf);
    else
      k_rms<<<NTOK, 256, 0, stream>>>(xf32, n1g + l * C_, hbuf);
    // transpose Wqkv + Wproj in one launch
    k_tr2<<<3072 + 1024, dim3(32, 8), 0, stream>>>(
        Wqkv + (size_t)l * C_ * 3 * C_, wT, C_, 3 * C_, 3072,
        Wpro + (size_t)l * C_ * C_, wTp, C_, C_);
    // qkv = h @ Wqkv
    k_gemm_bt<0><<<dim3(NTOK / 128, 3 * C_ / 128, 1), 256, 0, stream>>>(
        hbuf, wT, qkv, nullptr, nullptr, 3 * C_, C_);
    // gates from h
    k_gate<<<NTOK / 4, 256, 0, stream>>>(hbuf, gW + (size_t)l * C_ * 3, gb + l * 3, gates);
    // fused attention
    k_vt<<<dim3(64, 2, 32), dim3(32, 8), 0, stream>>>(qkv, Vt);
    k_attn<<<1024, 256, 0, stream>>>(qkv, Vt, obuf);
    // x += gate0 * (o @ Wproj)   [split-K=2, f32 atomic into residual]
    k_gemm_bt<1><<<dim3(NTOK / 128, C_ / 128, 2), 256, 0, stream>>>(
        obuf, wTp, nullptr, xf32, gates, C_, C_);
    // x += gate2*ret; h2 = rms(x)*g2   [fused]
    k_rms2mix<<<NTOK, 256, 0, stream>>>(xf32, gates, retb + (size_t)l * B_ * C_,
                                        n2g + l * C_, hbuf);
    // transpose fg + fu in one launch
    k_tr2<<<4096 + 4096, dim3(32, 8), 0, stream>>>(
        fgW + (size_t)l * C_ * F_, wT, C_, F_, 4096,
        fuW + (size_t)l * C_ * F_, wT2, C_, F_);
    // gbuf = silu(h2@Wg) * (h2@Wu)
    k_gemm_swiglu<<<dim3(NTOK / 128, F_ / 128), 256, 0, stream>>>(
        hbuf, wT, wT2, gbuf, F_, C_);
    // fd^T -> hbuf (h2 dead after swiglu)
    k_tr1<<<4096, dim3(32, 8), 0, stream>>>(fdW + (size_t)l * F_ * C_, hbuf, F_, C_);
    // x += gbuf @ Wd   [split-K=2, f32 atomic into residual]
    k_gemm_bt<2><<<dim3(NTOK / 128, C_ / 128, 2), 256, 0, stream>>>(
        gbuf, hbuf, nullptr, xf32, nullptr, C_, F_);
  }

  k_copyf<<<NELEM / 256, 256, 0, stream>>>(xf32, (float*)d_out);
}